// Round 1
// baseline (115.681 us; speedup 1.0000x reference)
//
#include <hip/hip_runtime.h>
#include <math.h>

// Problem constants
constexpr int B_  = 4;
constexpr int C_  = 256;
constexpr int HW_ = 4096;   // 64*64
constexpr int CR_ = 16;     // c / RED
constexpr int CQ_ = 32;     // c / 8
constexpr int NCC = 8;      // channel chunks for partial spatial stats
constexpr int CHK = 32;     // channels per chunk

__device__ __forceinline__ float sigmoidf_(float x){ return 1.f/(1.f+expf(-x)); }

// ---- A: per (b,c) mean & max over hw. grid = B*C blocks, 256 thr ----
__global__ void kA(const float* __restrict__ x, float* __restrict__ avg, float* __restrict__ mxv){
  int bc = blockIdx.x;
  const float4* r4 = (const float4*)(x + (size_t)bc*HW_);
  float s = 0.f, m = -INFINITY;
  for (int i = threadIdx.x; i < HW_/4; i += 256){
    float4 v = r4[i];
    s += v.x+v.y+v.z+v.w;
    m = fmaxf(m, fmaxf(fmaxf(v.x,v.y), fmaxf(v.z,v.w)));
  }
  for (int off = 32; off; off >>= 1){
    s += __shfl_down(s, off);
    m = fmaxf(m, __shfl_down(m, off));
  }
  __shared__ float ss[4], sm[4];
  int w = threadIdx.x >> 6, lane = threadIdx.x & 63;
  if (!lane){ ss[w] = s; sm[w] = m; }
  __syncthreads();
  if (!threadIdx.x){
    avg[bc] = (ss[0]+ss[1]+ss[2]+ss[3]) * (1.f/HW_);
    mxv[bc] = fmaxf(fmaxf(sm[0],sm[1]), fmaxf(sm[2],sm[3]));
  }
}

// ---- B: ch_att = sigmoid(mlp(avg)+mlp(max)). grid = B blocks, 256 thr ----
__global__ void kB(const float* __restrict__ avg, const float* __restrict__ mxv,
                   const float* __restrict__ w1, const float* __restrict__ w2,
                   float* __restrict__ att){
  int b = blockIdx.x, t = threadIdx.x;
  __shared__ float sa[C_], sm[C_], hs[CR_];
  sa[t] = avg[b*C_+t]; sm[t] = mxv[b*C_+t];
  __syncthreads();
  if (t < CR_){
    float ha = 0.f, hm = 0.f;
    for (int i = 0; i < C_; i++){ float w = w1[t*C_+i]; ha += w*sa[i]; hm += w*sm[i]; }
    hs[t] = fmaxf(ha, 0.f) + fmaxf(hm, 0.f);   // relu(h_avg)+relu(h_max), shared w2
  }
  __syncthreads();
  float o = 0.f;
  for (int h = 0; h < CR_; h++) o += hs[h]*w2[t*CR_+h];   // w2 is [C, CR]
  att[b*C_+t] = sigmoidf_(o);
}

// ---- C: partial per-pixel channel sum/max of x*att, over CHK-channel chunks.
//      grid = B*NCC*16 = 512 blocks of 64 thr (thread = one float4 of pixels) ----
__global__ void kC(const float* __restrict__ x, const float* __restrict__ att,
                   float* __restrict__ psum, float* __restrict__ pmax){
  int bx = blockIdx.x;
  int b = bx >> 7, rem = bx & 127, cc = rem >> 4, tile = rem & 15;
  int t = threadIdx.x;
  __shared__ float satt[CHK];
  if (t < CHK) satt[t] = att[b*C_ + cc*CHK + t];
  __syncthreads();
  int p4 = tile*64 + t;                       // float4 index, 0..1023
  const float4* x4 = (const float4*)(x + (size_t)(b*C_ + cc*CHK)*HW_);
  float4 s = {0.f,0.f,0.f,0.f};
  float4 m = {-INFINITY,-INFINITY,-INFINITY,-INFINITY};
  for (int j = 0; j < CHK; j++){
    float a = satt[j];
    float4 v = x4[(size_t)j*(HW_/4) + p4];
    float vx=v.x*a, vy=v.y*a, vz=v.z*a, vw=v.w*a;
    s.x+=vx; s.y+=vy; s.z+=vz; s.w+=vw;
    m.x=fmaxf(m.x,vx); m.y=fmaxf(m.y,vy); m.z=fmaxf(m.z,vz); m.w=fmaxf(m.w,vw);
  }
  ((float4*)psum)[(size_t)(b*NCC+cc)*(HW_/4) + p4] = s;
  ((float4*)pmax)[(size_t)(b*NCC+cc)*(HW_/4) + p4] = m;
}

// ---- D: combine partials -> 7x7 conv -> sigmoid -> out = x*att*sig.
//      grid = B*16rowtiles*4cparts = 256 blocks, 256 thr (thread = one pixel) ----
__global__ void kD(const float* __restrict__ x, const float* __restrict__ att,
                   const float* __restrict__ psum, const float* __restrict__ pmax,
                   const float* __restrict__ wsp, float* __restrict__ out){
  int bx = blockIdx.x;
  int b = bx >> 6, rem = bx & 63, rt = rem >> 2, cp = rem & 3;
  int t = threadIdx.x;
  __shared__ float savg[10][64], smax[10][64], satt[64], swsp[98];
  if (t < 98) swsp[t] = wsp[t];
  if (t < 64) satt[t] = att[b*C_ + cp*64 + t];
  for (int idx = t; idx < 640; idx += 256){
    int row = idx >> 6, col = idx & 63;
    int gr = rt*4 - 3 + row;                  // global image row (zero-padded)
    float s = 0.f, m = 0.f;
    if ((unsigned)gr < 64u){
      float mm = -INFINITY;
      for (int c2 = 0; c2 < NCC; c2++){
        s  += psum[(size_t)(b*NCC+c2)*HW_ + gr*64 + col];
        mm = fmaxf(mm, pmax[(size_t)(b*NCC+c2)*HW_ + gr*64 + col]);
      }
      m = mm; s *= (1.f/C_);
    }
    savg[row][col] = s; smax[row][col] = m;
  }
  __syncthreads();
  int trow = t >> 6, col = t & 63;
  float acc = 0.f;
  for (int ky = 0; ky < 7; ky++){
    int ly = trow + ky;
    for (int kx = 0; kx < 7; kx++){
      int gx = col - 3 + kx;
      if ((unsigned)gx < 64u)
        acc += savg[ly][gx]*swsp[ky*7+kx] + smax[ly][gx]*swsp[49+ky*7+kx];
    }
  }
  float sg = sigmoidf_(acc);
  size_t pbase = (size_t)(rt*4 + trow)*64 + col;
  for (int j = 0; j < 64; j++){
    size_t idx = (size_t)(b*C_ + cp*64 + j)*HW_ + pbase;
    out[idx] = x[idx]*satt[j]*sg;
  }
}

// ---- Gated non-local attention path (runs only when gamma != 0) ----
// E: q,k,v = 1x1 convs of x3. grid-stride over 512 tiles of 32 px.
__global__ void kE(const float* __restrict__ gamma, const float* __restrict__ x3,
                   const float* __restrict__ wq, const float* __restrict__ bq,
                   const float* __restrict__ wk, const float* __restrict__ bk,
                   const float* __restrict__ wv, const float* __restrict__ bv,
                   float* __restrict__ qb, float* __restrict__ kb, float* __restrict__ vb){
  if (gamma[0] == 0.f) return;
  int t = threadIdx.x;
  __shared__ float sx[C_*32];                 // [c][px], 32KB
  for (int bx = blockIdx.x; bx < 512; bx += gridDim.x){
    int b = bx >> 7, tile = bx & 127, p0 = tile*32;
    for (int idx = t; idx < C_*32; idx += 256){
      int c = idx >> 5, px = idx & 31;
      sx[idx] = x3[(size_t)(b*C_+c)*HW_ + p0 + px];
    }
    __syncthreads();
    for (int oi = t; oi < CQ_*32; oi += 256){
      int o = oi >> 5, px = oi & 31;
      float aq = bq[o], ak = bk[o];
      for (int c = 0; c < C_; c++){ float xv = sx[c*32+px]; aq += xv*wq[o*C_+c]; ak += xv*wk[o*C_+c]; }
      qb[(size_t)(b*CQ_+o)*HW_ + p0 + px] = aq;
      kb[(size_t)(b*CQ_+o)*HW_ + p0 + px] = ak;
    }
    for (int oi = t; oi < C_*32; oi += 256){
      int o = oi >> 5, px = oi & 31;
      float av = bv[o];
      for (int c = 0; c < C_; c++) av += sx[c*32+px]*wv[o*C_+c];
      vb[(size_t)(b*C_+o)*HW_ + p0 + px] = av;
    }
    __syncthreads();
  }
}

// F: softmax(q_i . k) then out[c,i] = sum_j p_j v[c,j]. One query per block iter.
__global__ void kF(const float* __restrict__ gamma, const float* __restrict__ qb,
                   const float* __restrict__ kb, const float* __restrict__ vb,
                   float* __restrict__ ab){
  if (gamma[0] == 0.f) return;
  __shared__ float sq[CQ_];
  __shared__ float sl[HW_];
  __shared__ float red[8];
  int t = threadIdx.x;
  for (int gi = blockIdx.x; gi < B_*HW_; gi += gridDim.x){
    int b = gi >> 12, i = gi & (HW_-1);
    if (t < CQ_) sq[t] = qb[(size_t)(b*CQ_+t)*HW_ + i];
    __syncthreads();
    float lmax = -INFINITY;
    for (int j = t; j < HW_; j += 256){
      float l = 0.f;
      for (int d = 0; d < CQ_; d++) l += sq[d]*kb[(size_t)(b*CQ_+d)*HW_ + j];
      sl[j] = l; lmax = fmaxf(lmax, l);
    }
    for (int off = 32; off; off >>= 1) lmax = fmaxf(lmax, __shfl_down(lmax, off));
    if (!(t & 63)) red[t>>6] = lmax;
    __syncthreads();
    float M = fmaxf(fmaxf(red[0],red[1]), fmaxf(red[2],red[3]));
    float lsum = 0.f;
    for (int j = t; j < HW_; j += 256){ float p = expf(sl[j]-M); sl[j] = p; lsum += p; }
    for (int off = 32; off; off >>= 1) lsum += __shfl_down(lsum, off);
    if (!(t & 63)) red[4+(t>>6)] = lsum;
    __syncthreads();
    float inv = 1.f/(red[4]+red[5]+red[6]+red[7]);
    float acc = 0.f;
    const float* vrow = vb + (size_t)(b*C_+t)*HW_;
    for (int j = 0; j < HW_; j++) acc += sl[j]*vrow[j];
    ab[(size_t)(b*C_+t)*HW_ + i] = acc*inv;
    __syncthreads();
  }
}

// G: out += gamma * attn_out (gated).
__global__ void kG(const float* __restrict__ gamma, const float* __restrict__ ab,
                   float* __restrict__ out){
  float g = gamma[0];
  if (g == 0.f) return;
  size_t n = (size_t)B_*C_*HW_;
  for (size_t i = (size_t)blockIdx.x*256 + threadIdx.x; i < n; i += (size_t)256*gridDim.x)
    out[i] += g*ab[i];
}

extern "C" void kernel_launch(void* const* d_in, const int* in_sizes, int n_in,
                              void* d_out, int out_size, void* d_ws, size_t ws_size,
                              hipStream_t stream){
  const float* x   = (const float*)d_in[0];
  const float* w1  = (const float*)d_in[1];
  const float* w2  = (const float*)d_in[2];
  const float* wsp = (const float*)d_in[3];
  const float* wq  = (const float*)d_in[4];
  const float* bq  = (const float*)d_in[5];
  const float* wk  = (const float*)d_in[6];
  const float* bk  = (const float*)d_in[7];
  const float* wv  = (const float*)d_in[8];
  const float* bv  = (const float*)d_in[9];
  const float* gm  = (const float*)d_in[10];
  float* out = (float*)d_out;
  float* ws  = (float*)d_ws;

  float* avg  = ws;                       // 1024
  float* mxv  = avg  + B_*C_;             // 1024
  float* att  = mxv  + B_*C_;             // 1024
  float* psum = att  + B_*C_;             // B*NCC*HW = 131072
  float* pmax = psum + B_*NCC*HW_;        // 131072
  float* qb   = pmax + B_*NCC*HW_;        // B*CQ*HW = 524288 (gated)
  float* kb   = qb   + B_*CQ_*HW_;        // 524288 (gated)
  float* vb   = kb   + B_*CQ_*HW_;        // B*C*HW = 4194304 (gated)
  float* ab   = vb   + (size_t)B_*C_*HW_; // 4194304 (gated)
  size_t need_attn = (size_t)((ab + (size_t)B_*C_*HW_) - ws) * sizeof(float);

  kA<<<B_*C_, 256, 0, stream>>>(x, avg, mxv);
  kB<<<B_,    256, 0, stream>>>(avg, mxv, w1, w2, att);
  kC<<<512,    64, 0, stream>>>(x, att, psum, pmax);
  kD<<<256,   256, 0, stream>>>(x, att, psum, pmax, wsp, out);

  // Non-local attention, correct for any gamma; early-exits in-kernel when gamma==0.
  if (ws_size >= need_attn){
    kE<<<256, 256, 0, stream>>>(gm, out, wq, bq, wk, bk, wv, bv, qb, kb, vb);
    kF<<<256, 256, 0, stream>>>(gm, qb, kb, vb, ab);
    kG<<<256, 256, 0, stream>>>(gm, ab, out);
  }
}

// Round 2
// 113.838 us; speedup vs baseline: 1.0162x; 1.0162x over previous
//
#include <hip/hip_runtime.h>
#include <math.h>

// Problem constants
constexpr int B_  = 4;
constexpr int C_  = 256;
constexpr int HW_ = 4096;   // 64*64
constexpr int CR_ = 16;     // c / RED
constexpr int CQ_ = 32;     // c / 8
constexpr int NCC = 16;     // channel chunks for partial spatial stats
constexpr int CHK = 16;     // channels per chunk

__device__ __forceinline__ float sigmoidf_(float x){ return 1.f/(1.f+expf(-x)); }

// ---- A: per (b,c) mean & max over hw. grid = B*C blocks, 256 thr ----
__global__ void kA(const float* __restrict__ x, float* __restrict__ avg, float* __restrict__ mxv){
  int bc = blockIdx.x;
  const float4* r4 = (const float4*)(x + (size_t)bc*HW_);
  float s = 0.f, m = -INFINITY;
  for (int i = threadIdx.x; i < HW_/4; i += 256){
    float4 v = r4[i];
    s += v.x+v.y+v.z+v.w;
    m = fmaxf(m, fmaxf(fmaxf(v.x,v.y), fmaxf(v.z,v.w)));
  }
  for (int off = 32; off; off >>= 1){
    s += __shfl_down(s, off);
    m = fmaxf(m, __shfl_down(m, off));
  }
  __shared__ float ss[4], sm[4];
  int w = threadIdx.x >> 6, lane = threadIdx.x & 63;
  if (!lane){ ss[w] = s; sm[w] = m; }
  __syncthreads();
  if (!threadIdx.x){
    avg[bc] = (ss[0]+ss[1]+ss[2]+ss[3]) * (1.f/HW_);
    mxv[bc] = fmaxf(fmaxf(sm[0],sm[1]), fmaxf(sm[2],sm[3]));
  }
}

// ---- B: ch_att = sigmoid(mlp(avg)+mlp(max)). grid = B blocks, 256 thr ----
__global__ void kB(const float* __restrict__ avg, const float* __restrict__ mxv,
                   const float* __restrict__ w1, const float* __restrict__ w2,
                   float* __restrict__ att){
  int b = blockIdx.x, t = threadIdx.x;
  __shared__ float sa[C_], sm[C_], hs[CR_];
  sa[t] = avg[b*C_+t]; sm[t] = mxv[b*C_+t];
  __syncthreads();
  if (t < CR_){
    float ha = 0.f, hm = 0.f;
    for (int i = 0; i < C_; i++){ float w = w1[t*C_+i]; ha += w*sa[i]; hm += w*sm[i]; }
    hs[t] = fmaxf(ha, 0.f) + fmaxf(hm, 0.f);   // relu(h_avg)+relu(h_max), shared w2
  }
  __syncthreads();
  float o = 0.f;
  for (int h = 0; h < CR_; h++) o += hs[h]*w2[t*CR_+h];   // w2 is [C, CR]
  att[b*C_+t] = sigmoidf_(o);
}

// ---- C: partial per-pixel channel sum/max of x*att over CHK-channel chunks.
//      grid = B*NCC*4tiles = 256 blocks, 256 thr (thread = one float4 of pixels) ----
__global__ void kC(const float* __restrict__ x, const float* __restrict__ att,
                   float* __restrict__ psum, float* __restrict__ pmax){
  int bx = blockIdx.x;
  int b = bx >> 6, rem = bx & 63, cc = rem >> 2, tile = rem & 3;
  int t = threadIdx.x;
  __shared__ float satt[CHK];
  if (t < CHK) satt[t] = att[b*C_ + cc*CHK + t];
  __syncthreads();
  int p4 = tile*256 + t;                      // float4 index, 0..1023
  const float4* x4 = (const float4*)(x + (size_t)(b*C_ + cc*CHK)*HW_);
  float4 s = {0.f,0.f,0.f,0.f};
  float4 m = {-INFINITY,-INFINITY,-INFINITY,-INFINITY};
  #pragma unroll
  for (int j = 0; j < CHK; j++){
    float a = satt[j];
    float4 v = x4[(size_t)j*(HW_/4) + p4];
    float vx=v.x*a, vy=v.y*a, vz=v.z*a, vw=v.w*a;
    s.x+=vx; s.y+=vy; s.z+=vz; s.w+=vw;
    m.x=fmaxf(m.x,vx); m.y=fmaxf(m.y,vy); m.z=fmaxf(m.z,vz); m.w=fmaxf(m.w,vw);
  }
  ((float4*)psum)[(size_t)(b*NCC+cc)*(HW_/4) + p4] = s;
  ((float4*)pmax)[(size_t)(b*NCC+cc)*(HW_/4) + p4] = m;
}

// ---- D: combine partials -> 7x7 conv -> sigmoid -> out = x*att*sig, float4.
//      grid = B*16rowtiles*4cparts = 256 blocks, 256 thr ----
__global__ void kD(const float* __restrict__ x, const float* __restrict__ att,
                   const float* __restrict__ psum, const float* __restrict__ pmax,
                   const float* __restrict__ wsp, float* __restrict__ out){
  int bx = blockIdx.x;
  int b = bx >> 6, rem = bx & 63, rt = rem >> 2, cp = rem & 3;
  int t = threadIdx.x;
  __shared__ float savg[10][64], smax[10][64], ssig[4][64], satt[64], swsp[98];
  if (t < 98) swsp[t] = wsp[t];
  if (t < 64) satt[t] = att[b*C_ + cp*64 + t];
  for (int idx = t; idx < 640; idx += 256){
    int row = idx >> 6, col = idx & 63;
    int gr = rt*4 - 3 + row;                  // global image row (zero-padded)
    float s = 0.f, m = 0.f;
    if ((unsigned)gr < 64u){
      float mm = -INFINITY;
      #pragma unroll
      for (int c2 = 0; c2 < NCC; c2++){
        s  += psum[((b*NCC+c2)<<12) + (gr<<6) + col];
        mm = fmaxf(mm, pmax[((b*NCC+c2)<<12) + (gr<<6) + col]);
      }
      m = mm; s *= (1.f/C_);
    }
    savg[row][col] = s; smax[row][col] = m;
  }
  __syncthreads();
  int trow = t >> 6, col = t & 63;
  float acc = 0.f;
  #pragma unroll
  for (int ky = 0; ky < 7; ky++){
    #pragma unroll
    for (int kx = 0; kx < 7; kx++){
      int gx = col - 3 + kx;
      if ((unsigned)gx < 64u)
        acc += savg[trow+ky][gx]*swsp[ky*7+kx] + smax[trow+ky][gx]*swsp[49+ky*7+kx];
    }
  }
  ssig[trow][col] = sigmoidf_(acc);
  __syncthreads();
  // vectorized scaling: tile = 4 rows x 64 cols = 64 float4 positions
  int f4id = t & 63;                          // r = f4id>>4, q = f4id&15
  float4 sg4 = ((const float4*)ssig)[f4id];
  int imgo = rt*64 + f4id;                    // float4 index within image
  const float4* x4 = (const float4*)x;
  float4* o4 = (float4*)out;
  #pragma unroll
  for (int jj = 0; jj < 16; jj++){
    int lc = (t>>6) + jj*4;                   // local channel 0..63 (wave-uniform)
    float a = satt[lc];
    size_t g = (size_t)(b*C_ + cp*64 + lc)*(HW_/4) + imgo;
    float4 v = x4[g];
    float4 r;
    r.x = v.x*a*sg4.x; r.y = v.y*a*sg4.y; r.z = v.z*a*sg4.z; r.w = v.w*a*sg4.w;
    o4[g] = r;
  }
}

// ---- Gated non-local attention path (runs only when gamma != 0) ----
__global__ void kE(const float* __restrict__ gamma, const float* __restrict__ x3,
                   const float* __restrict__ wq, const float* __restrict__ bq,
                   const float* __restrict__ wk, const float* __restrict__ bk,
                   const float* __restrict__ wv, const float* __restrict__ bv,
                   float* __restrict__ qb, float* __restrict__ kb, float* __restrict__ vb){
  if (gamma[0] == 0.f) return;
  int t = threadIdx.x;
  __shared__ float sx[C_*32];                 // [c][px], 32KB
  for (int bx = blockIdx.x; bx < 512; bx += gridDim.x){
    int b = bx >> 7, tile = bx & 127, p0 = tile*32;
    for (int idx = t; idx < C_*32; idx += 256){
      int c = idx >> 5, px = idx & 31;
      sx[idx] = x3[(size_t)(b*C_+c)*HW_ + p0 + px];
    }
    __syncthreads();
    for (int oi = t; oi < CQ_*32; oi += 256){
      int o = oi >> 5, px = oi & 31;
      float aq = bq[o], ak = bk[o];
      for (int c = 0; c < C_; c++){ float xv = sx[c*32+px]; aq += xv*wq[o*C_+c]; ak += xv*wk[o*C_+c]; }
      qb[(size_t)(b*CQ_+o)*HW_ + p0 + px] = aq;
      kb[(size_t)(b*CQ_+o)*HW_ + p0 + px] = ak;
    }
    for (int oi = t; oi < C_*32; oi += 256){
      int o = oi >> 5, px = oi & 31;
      float av = bv[o];
      for (int c = 0; c < C_; c++) av += sx[c*32+px]*wv[o*C_+c];
      vb[(size_t)(b*C_+o)*HW_ + p0 + px] = av;
    }
    __syncthreads();
  }
}

__global__ void kF(const float* __restrict__ gamma, const float* __restrict__ qb,
                   const float* __restrict__ kb, const float* __restrict__ vb,
                   float* __restrict__ ab){
  if (gamma[0] == 0.f) return;
  __shared__ float sq[CQ_];
  __shared__ float sl[HW_];
  __shared__ float red[8];
  int t = threadIdx.x;
  for (int gi = blockIdx.x; gi < B_*HW_; gi += gridDim.x){
    int b = gi >> 12, i = gi & (HW_-1);
    if (t < CQ_) sq[t] = qb[(size_t)(b*CQ_+t)*HW_ + i];
    __syncthreads();
    float lmax = -INFINITY;
    for (int j = t; j < HW_; j += 256){
      float l = 0.f;
      for (int d = 0; d < CQ_; d++) l += sq[d]*kb[(size_t)(b*CQ_+d)*HW_ + j];
      sl[j] = l; lmax = fmaxf(lmax, l);
    }
    for (int off = 32; off; off >>= 1) lmax = fmaxf(lmax, __shfl_down(lmax, off));
    if (!(t & 63)) red[t>>6] = lmax;
    __syncthreads();
    float M = fmaxf(fmaxf(red[0],red[1]), fmaxf(red[2],red[3]));
    float lsum = 0.f;
    for (int j = t; j < HW_; j += 256){ float p = expf(sl[j]-M); sl[j] = p; lsum += p; }
    for (int off = 32; off; off >>= 1) lsum += __shfl_down(lsum, off);
    if (!(t & 63)) red[4+(t>>6)] = lsum;
    __syncthreads();
    float inv = 1.f/(red[4]+red[5]+red[6]+red[7]);
    float acc = 0.f;
    const float* vrow = vb + (size_t)(b*C_+t)*HW_;
    for (int j = 0; j < HW_; j++) acc += sl[j]*vrow[j];
    ab[(size_t)(b*C_+t)*HW_ + i] = acc*inv;
    __syncthreads();
  }
}

__global__ void kG(const float* __restrict__ gamma, const float* __restrict__ ab,
                   float* __restrict__ out){
  float g = gamma[0];
  if (g == 0.f) return;
  size_t n = (size_t)B_*C_*HW_;
  for (size_t i = (size_t)blockIdx.x*256 + threadIdx.x; i < n; i += (size_t)256*gridDim.x)
    out[i] += g*ab[i];
}

extern "C" void kernel_launch(void* const* d_in, const int* in_sizes, int n_in,
                              void* d_out, int out_size, void* d_ws, size_t ws_size,
                              hipStream_t stream){
  const float* x   = (const float*)d_in[0];
  const float* w1  = (const float*)d_in[1];
  const float* w2  = (const float*)d_in[2];
  const float* wsp = (const float*)d_in[3];
  const float* wq  = (const float*)d_in[4];
  const float* bq  = (const float*)d_in[5];
  const float* wk  = (const float*)d_in[6];
  const float* bk  = (const float*)d_in[7];
  const float* wv  = (const float*)d_in[8];
  const float* bv  = (const float*)d_in[9];
  const float* gm  = (const float*)d_in[10];
  float* out = (float*)d_out;
  float* ws  = (float*)d_ws;

  float* avg  = ws;                       // 1024
  float* mxv  = avg  + B_*C_;             // 1024
  float* att  = mxv  + B_*C_;             // 1024
  float* psum = att  + B_*C_;             // B*NCC*HW = 262144
  float* pmax = psum + B_*NCC*HW_;        // 262144
  float* qb   = pmax + B_*NCC*HW_;        // B*CQ*HW = 524288 (gated)
  float* kb   = qb   + B_*CQ_*HW_;        // 524288 (gated)
  float* vb   = kb   + B_*CQ_*HW_;        // B*C*HW = 4194304 (gated)
  float* ab   = vb   + (size_t)B_*C_*HW_; // 4194304 (gated)
  size_t need_attn = (size_t)((ab + (size_t)B_*C_*HW_) - ws) * sizeof(float);

  kA<<<B_*C_, 256, 0, stream>>>(x, avg, mxv);
  kB<<<B_,    256, 0, stream>>>(avg, mxv, w1, w2, att);
  kC<<<256,   256, 0, stream>>>(x, att, psum, pmax);
  kD<<<256,   256, 0, stream>>>(x, att, psum, pmax, wsp, out);

  // Non-local attention, correct for any gamma; early-exits in-kernel when gamma==0.
  if (ws_size >= need_attn){
    kE<<<256, 256, 0, stream>>>(gm, out, wq, bq, wk, bk, wv, bv, qb, kb, vb);
    kF<<<256, 256, 0, stream>>>(gm, qb, kb, vb, ab);
    kG<<<256, 256, 0, stream>>>(gm, ab, out);
  }
}

// Round 3
// 109.175 us; speedup vs baseline: 1.0596x; 1.0427x over previous
//
#include <hip/hip_runtime.h>
#include <math.h>

// Problem constants
constexpr int B_  = 4;
constexpr int C_  = 256;
constexpr int HW_ = 4096;   // 64*64
constexpr int CR_ = 16;     // c / RED
constexpr int CQ_ = 32;     // c / 8

__device__ __forceinline__ float sigmoidf_(float x){ return 1.f/(1.f+expf(-x)); }

// Inline channel-attention MLP: all 256 threads cooperate, result in satt[256].
// Needs LDS scratch: sa/sm/pa/pm[256], hs[16]. Must be followed by __syncthreads()
// before satt is consumed (done inside).
__device__ __forceinline__ void ch_att_inline(
    int b, int t,
    const float* __restrict__ avg, const float* __restrict__ mxv,
    const float* __restrict__ w1,  const float* __restrict__ w2,
    float* sa, float* sm, float* pa, float* pm, float* hs, float* satt){
  sa[t] = avg[b*C_+t]; sm[t] = mxv[b*C_+t];
  __syncthreads();
  int h = t >> 4, seg = t & 15;                 // 16 hidden x 16 channel-segments
  float qa = 0.f, qm = 0.f;
  #pragma unroll
  for (int c2 = 0; c2 < 16; c2++){
    int c = seg*16 + c2;
    float w = w1[h*C_ + c];
    qa += w*sa[c]; qm += w*sm[c];
  }
  pa[t] = qa; pm[t] = qm;
  __syncthreads();
  if (t < CR_){
    float ha = 0.f, hm = 0.f;
    #pragma unroll
    for (int s = 0; s < 16; s++){ ha += pa[t*16+s]; hm += pm[t*16+s]; }
    hs[t] = fmaxf(ha, 0.f) + fmaxf(hm, 0.f);    // relu(h_avg)+relu(h_max), shared w2
  }
  __syncthreads();
  float o = 0.f;
  #pragma unroll
  for (int h2 = 0; h2 < CR_; h2++) o += hs[h2]*w2[t*CR_+h2];   // w2 is [C, CR]
  satt[t] = sigmoidf_(o);
  __syncthreads();
}

// ---- A: per (b,c) mean & max over hw. grid = B*C blocks, 256 thr ----
__global__ void kA(const float* __restrict__ x, float* __restrict__ avg, float* __restrict__ mxv){
  int bc = blockIdx.x;
  const float4* r4 = (const float4*)(x + (size_t)bc*HW_);
  float s = 0.f, m = -INFINITY;
  for (int i = threadIdx.x; i < HW_/4; i += 256){
    float4 v = r4[i];
    s += v.x+v.y+v.z+v.w;
    m = fmaxf(m, fmaxf(fmaxf(v.x,v.y), fmaxf(v.z,v.w)));
  }
  for (int off = 32; off; off >>= 1){
    s += __shfl_down(s, off);
    m = fmaxf(m, __shfl_down(m, off));
  }
  __shared__ float ss[4], sm[4];
  int w = threadIdx.x >> 6, lane = threadIdx.x & 63;
  if (!lane){ ss[w] = s; sm[w] = m; }
  __syncthreads();
  if (!threadIdx.x){
    avg[bc] = (ss[0]+ss[1]+ss[2]+ss[3]) * (1.f/HW_);
    mxv[bc] = fmaxf(fmaxf(sm[0],sm[1]), fmaxf(sm[2],sm[3]));
  }
}

// ---- BC: ch_att inline, then FULL per-pixel channel mean/max of x*att.
//      grid = B*64 rows = 256 blocks, 256 thr. Block = (b, image row r).
//      Thread (cg=t>>4, q=t&15): channel group cg, float4-pixel q. ----
__global__ void kBC(const float* __restrict__ x,
                    const float* __restrict__ avg, const float* __restrict__ mxv,
                    const float* __restrict__ w1,  const float* __restrict__ w2,
                    float* __restrict__ avgs, float* __restrict__ maxs){
  int b = blockIdx.x >> 6, r = blockIdx.x & 63, t = threadIdx.x;
  __shared__ float sa[C_], sm[C_], pa[C_], pm[C_], hs[CR_], satt[C_];
  __shared__ float4 rs[16][16], rm[16][16];
  ch_att_inline(b, t, avg, mxv, w1, w2, sa, sm, pa, pm, hs, satt);

  int cg = t >> 4, q = t & 15;
  const float4* x4 = (const float4*)x;
  float4 s = {0.f,0.f,0.f,0.f};
  float4 m = {-INFINITY,-INFINITY,-INFINITY,-INFINITY};
  #pragma unroll
  for (int j = 0; j < 16; j++){
    int c = cg*16 + j;
    float a = satt[c];
    float4 v = x4[(size_t)(b*C_+c)*(HW_/4) + (r<<4) + q];
    float vx=v.x*a, vy=v.y*a, vz=v.z*a, vw=v.w*a;
    s.x+=vx; s.y+=vy; s.z+=vz; s.w+=vw;
    m.x=fmaxf(m.x,vx); m.y=fmaxf(m.y,vy); m.z=fmaxf(m.z,vz); m.w=fmaxf(m.w,vw);
  }
  rs[cg][q] = s; rm[cg][q] = m;
  __syncthreads();
  if (t < 16){
    float4 S = {0.f,0.f,0.f,0.f};
    float4 M = {-INFINITY,-INFINITY,-INFINITY,-INFINITY};
    #pragma unroll
    for (int g = 0; g < 16; g++){
      float4 a = rs[g][t], b2 = rm[g][t];
      S.x+=a.x; S.y+=a.y; S.z+=a.z; S.w+=a.w;
      M.x=fmaxf(M.x,b2.x); M.y=fmaxf(M.y,b2.y); M.z=fmaxf(M.z,b2.z); M.w=fmaxf(M.w,b2.w);
    }
    S.x*=(1.f/C_); S.y*=(1.f/C_); S.z*=(1.f/C_); S.w*=(1.f/C_);
    ((float4*)(avgs + b*HW_ + r*64))[t] = S;
    ((float4*)(maxs + b*HW_ + r*64))[t] = M;
  }
}

// ---- D: ch_att inline, stage spatial stats + halo, 7x7 conv -> sigmoid,
//      out = x*att*sig (float4). grid = B*16rowtiles*4cparts = 256 blocks. ----
__global__ void kD2(const float* __restrict__ x,
                    const float* __restrict__ avg, const float* __restrict__ mxv,
                    const float* __restrict__ w1,  const float* __restrict__ w2,
                    const float* __restrict__ avgs, const float* __restrict__ maxs,
                    const float* __restrict__ wsp, float* __restrict__ out){
  int bx = blockIdx.x;
  int b = bx >> 6, rem = bx & 63, rt = rem >> 2, cp = rem & 3;
  int t = threadIdx.x;
  __shared__ float sa[C_], sm[C_], pa[C_], pm[C_], hs[CR_], satt[C_];
  __shared__ float savg[10][64], smax[10][64], ssig[4][64], swsp[98];
  if (t < 98) swsp[t] = wsp[t];
  ch_att_inline(b, t, avg, mxv, w1, w2, sa, sm, pa, pm, hs, satt);

  for (int idx = t; idx < 640; idx += 256){
    int row = idx >> 6, col = idx & 63;
    int gr = rt*4 - 3 + row;                  // global image row (zero-padded)
    float s = 0.f, m = 0.f;
    if ((unsigned)gr < 64u){
      s = avgs[b*HW_ + gr*64 + col];
      m = maxs[b*HW_ + gr*64 + col];
    }
    savg[row][col] = s; smax[row][col] = m;
  }
  __syncthreads();
  int trow = t >> 6, col = t & 63;
  float acc = 0.f;
  #pragma unroll
  for (int ky = 0; ky < 7; ky++){
    #pragma unroll
    for (int kx = 0; kx < 7; kx++){
      int gx = col - 3 + kx;
      if ((unsigned)gx < 64u)
        acc += savg[trow+ky][gx]*swsp[ky*7+kx] + smax[trow+ky][gx]*swsp[49+ky*7+kx];
    }
  }
  ssig[trow][col] = sigmoidf_(acc);
  __syncthreads();
  // vectorized scaling: tile = 4 rows x 64 cols = 64 float4 positions
  int f4id = t & 63;
  float4 sg4 = ((const float4*)ssig)[f4id];
  int imgo = rt*64 + f4id;                    // float4 index within image
  const float4* x4 = (const float4*)x;
  float4* o4 = (float4*)out;
  #pragma unroll
  for (int jj = 0; jj < 16; jj++){
    int lc = (t>>6) + jj*4;                   // local channel 0..63 (wave-uniform)
    float a = satt[cp*64 + lc];
    size_t g = (size_t)(b*C_ + cp*64 + lc)*(HW_/4) + imgo;
    float4 v = x4[g];
    float4 rr;
    rr.x = v.x*a*sg4.x; rr.y = v.y*a*sg4.y; rr.z = v.z*a*sg4.z; rr.w = v.w*a*sg4.w;
    o4[g] = rr;
  }
}

// ---- Gated non-local attention path (runs only when gamma != 0) ----
__global__ void kE(const float* __restrict__ gamma, const float* __restrict__ x3,
                   const float* __restrict__ wq, const float* __restrict__ bq,
                   const float* __restrict__ wk, const float* __restrict__ bk,
                   const float* __restrict__ wv, const float* __restrict__ bv,
                   float* __restrict__ qb, float* __restrict__ kb, float* __restrict__ vb){
  if (gamma[0] == 0.f) return;
  int t = threadIdx.x;
  __shared__ float sx[C_*32];                 // [c][px], 32KB
  for (int bx = blockIdx.x; bx < 512; bx += gridDim.x){
    int b = bx >> 7, tile = bx & 127, p0 = tile*32;
    for (int idx = t; idx < C_*32; idx += 256){
      int c = idx >> 5, px = idx & 31;
      sx[idx] = x3[(size_t)(b*C_+c)*HW_ + p0 + px];
    }
    __syncthreads();
    for (int oi = t; oi < CQ_*32; oi += 256){
      int o = oi >> 5, px = oi & 31;
      float aq = bq[o], ak = bk[o];
      for (int c = 0; c < C_; c++){ float xv = sx[c*32+px]; aq += xv*wq[o*C_+c]; ak += xv*wk[o*C_+c]; }
      qb[(size_t)(b*CQ_+o)*HW_ + p0 + px] = aq;
      kb[(size_t)(b*CQ_+o)*HW_ + p0 + px] = ak;
    }
    for (int oi = t; oi < C_*32; oi += 256){
      int o = oi >> 5, px = oi & 31;
      float av = bv[o];
      for (int c = 0; c < C_; c++) av += sx[c*32+px]*wv[o*C_+c];
      vb[(size_t)(b*C_+o)*HW_ + p0 + px] = av;
    }
    __syncthreads();
  }
}

// F2: softmax(q_i . k), then out[b,c,i] += gamma * sum_j p_j v[c,j] (fuses old kG).
__global__ void kF2(const float* __restrict__ gamma, const float* __restrict__ qb,
                    const float* __restrict__ kb, const float* __restrict__ vb,
                    float* __restrict__ out){
  float g = gamma[0];
  if (g == 0.f) return;
  __shared__ float sq[CQ_];
  __shared__ float sl[HW_];
  __shared__ float red[8];
  int t = threadIdx.x;
  for (int gi = blockIdx.x; gi < B_*HW_; gi += gridDim.x){
    int b = gi >> 12, i = gi & (HW_-1);
    if (t < CQ_) sq[t] = qb[(size_t)(b*CQ_+t)*HW_ + i];
    __syncthreads();
    float lmax = -INFINITY;
    for (int j = t; j < HW_; j += 256){
      float l = 0.f;
      for (int d = 0; d < CQ_; d++) l += sq[d]*kb[(size_t)(b*CQ_+d)*HW_ + j];
      sl[j] = l; lmax = fmaxf(lmax, l);
    }
    for (int off = 32; off; off >>= 1) lmax = fmaxf(lmax, __shfl_down(lmax, off));
    if (!(t & 63)) red[t>>6] = lmax;
    __syncthreads();
    float M = fmaxf(fmaxf(red[0],red[1]), fmaxf(red[2],red[3]));
    float lsum = 0.f;
    for (int j = t; j < HW_; j += 256){ float p = expf(sl[j]-M); sl[j] = p; lsum += p; }
    for (int off = 32; off; off >>= 1) lsum += __shfl_down(lsum, off);
    if (!(t & 63)) red[4+(t>>6)] = lsum;
    __syncthreads();
    float inv = g/(red[4]+red[5]+red[6]+red[7]);
    float acc = 0.f;
    const float* vrow = vb + (size_t)(b*C_+t)*HW_;
    for (int j = 0; j < HW_; j++) acc += sl[j]*vrow[j];
    out[(size_t)(b*C_+t)*HW_ + i] += acc*inv;
    __syncthreads();
  }
}

extern "C" void kernel_launch(void* const* d_in, const int* in_sizes, int n_in,
                              void* d_out, int out_size, void* d_ws, size_t ws_size,
                              hipStream_t stream){
  const float* x   = (const float*)d_in[0];
  const float* w1  = (const float*)d_in[1];
  const float* w2  = (const float*)d_in[2];
  const float* wsp = (const float*)d_in[3];
  const float* wq  = (const float*)d_in[4];
  const float* bq  = (const float*)d_in[5];
  const float* wk  = (const float*)d_in[6];
  const float* bk  = (const float*)d_in[7];
  const float* wv  = (const float*)d_in[8];
  const float* bv  = (const float*)d_in[9];
  const float* gm  = (const float*)d_in[10];
  float* out = (float*)d_out;
  float* ws  = (float*)d_ws;

  float* avg  = ws;                       // 1024
  float* mxv  = avg  + B_*C_;             // 1024
  float* avgs = mxv  + B_*C_;             // B*HW = 16384
  float* maxs = avgs + B_*HW_;            // 16384
  float* qb   = maxs + B_*HW_;            // B*CQ*HW = 524288 (gated)
  float* kb   = qb   + B_*CQ_*HW_;        // 524288 (gated)
  float* vb   = kb   + B_*CQ_*HW_;        // B*C*HW = 4194304 (gated)
  size_t need_attn = (size_t)((vb + (size_t)B_*C_*HW_) - ws) * sizeof(float);

  kA <<<B_*C_, 256, 0, stream>>>(x, avg, mxv);
  kBC<<<256,   256, 0, stream>>>(x, avg, mxv, w1, w2, avgs, maxs);
  kD2<<<256,   256, 0, stream>>>(x, avg, mxv, w1, w2, avgs, maxs, wsp, out);

  // Non-local attention, correct for any gamma; early-exits in-kernel when gamma==0.
  if (ws_size >= need_attn){
    kE <<<256, 256, 0, stream>>>(gm, out, wq, bq, wk, bk, wv, bv, qb, kb, vb);
    kF2<<<256, 256, 0, stream>>>(gm, qb, kb, vb, out);
  }
}